// Round 2
// baseline (437.562 us; speedup 1.0000x reference)
//
#include <hip/hip_runtime.h>

// B=4096, D=64, DM=256, K=32, KA=16, S=50
#define B_N 4096
#define TB 8
#define SQUARINGS 8

// ---- workspace layout (float offsets); total ~4.72 MB ----
#define OFF_W5T  0        // 5 x [256 j][64 k]  transposed folded mats: q,klat,vlat,kcode,vcode
#define OFF_B5   81920    // 5 x [256]
#define OFF_KALL 83200    // [48][256] (rows 0..15 achart@Wk, 16..47 chart@Wk)
#define OFF_VALL 95488    // [48][256] (@Wv)
#define OFF_ANC  107776   // [48][64] anchors (achart then chart)
#define OFF_M    110848   // [256 k][64 d]  Wo @ form_W
#define OFF_G    127232   // [64][64] form_W^T form_W
#define OFF_RS   131328   // 1/sigma
#define OFF_FP   131392   // [4096][256] feat_pre
// end: 1179968 floats = 4.72 MB

// ---- k2 LDS layout (floats) ----
#define S_ZS    0         // [8][68]
#define S_AZS   544
#define S_ACZS  1088
#define S_RWS   1632      // [8][36]
#define S_ARWS  1920      // [8][20]
#define S_QFP   2080      // [8][260]
#define S_SW    4160      // [8][52]  0..15 achart, 16..47 chart, 48 lat, 49 code
#define S_RED   4576      // [8][16]  pL w0..3 | pC w0..3 | dL | dC
#define SMEM_K2 13200     // sigma block needs up to 13124

// ===================== K1: all weight folds, 2005 light blocks =====================
// Row-task: 256 threads = 64 j-lanes x 4 k-slices of 64; block reduce; store.
__global__ __launch_bounds__(256)
void k1_fold(const float* __restrict__ chart_emb, const float* __restrict__ a_chart_emb,
             const float* __restrict__ zW, const float* __restrict__ zb,
             const float* __restrict__ latW, const float* __restrict__ latb,
             const float* __restrict__ codeW, const float* __restrict__ codeb,
             const float* __restrict__ Wq, const float* __restrict__ Wk,
             const float* __restrict__ Wv, const float* __restrict__ Wo,
             const float* __restrict__ fW, const float* __restrict__ ach_anchor,
             const float* __restrict__ ch_anchor, float* __restrict__ ws) {
  __shared__ float red[256];
  const int t = threadIdx.x;
  const int b = blockIdx.x;

  if (b == 2004) {   // anchor copy [48][64]
    for (int e = t; e < 3072; e += 256) {
      int s = e >> 6, d = e & 63;
      ws[OFF_ANC + e] = (s < 16) ? ach_anchor[s * 64 + d] : ch_anchor[(s - 16) * 64 + d];
    }
    return;
  }

  const float* Arow; const float* Bm;
  int astride = 1, bstride = 256, jbase = 0, dstBase, dstStride = 1;
  if (b < 1300) {                       // W5T + biases: u in 0..4, 65 rows, 4 j-chunks
    int u = b / 260, r = b - u * 260;
    int i = r >> 2, jc = r & 3; jbase = jc * 64;
    const float* Amat = (u == 0) ? zW : (u <= 2 ? latW : codeW);
    const float* bias = (u == 0) ? zb : (u <= 2 ? latb : codeb);
    Bm = (u == 0) ? Wq : ((u == 1 || u == 3) ? Wk : Wv);
    if (i < 64) {
      Arow = Amat + i * 256;
      dstBase = OFF_W5T + u * 16384 + jbase * 64 + i;   // store transposed [j][i]
      dstStride = 64;
    } else {
      Arow = bias;
      dstBase = OFF_B5 + u * 256 + jbase;
    }
  } else if (b < 1684) {                // KALL/VALL: 96 rows x 4 j-chunks
    int rr = b - 1300; int row = rr >> 2, jc = rr & 3; jbase = jc * 64;
    int s = (row < 48) ? row : row - 48;
    Bm = (row < 48) ? Wk : Wv;
    Arow = (s < 16) ? (a_chart_emb + s * 256) : (chart_emb + (s - 16) * 256);
    dstBase = OFF_KALL + row * 256 + jbase;   // KALL then VALL contiguous
  } else if (b < 1940) {                // M: 256 rows (k-index), 64 outputs
    int i = b - 1684;
    Arow = Wo + i * 256; Bm = fW; bstride = 64;
    dstBase = OFF_M + i * 64;
  } else {                              // G: 64 rows
    int i = b - 1940;
    Arow = fW + i; astride = 64; Bm = fW; bstride = 64;
    dstBase = OFF_G + i * 64;
  }

  const int j = t & 63, ks = t >> 6;
  const float* ap = Arow + (ks * 64) * astride;
  const float* bp = Bm + (ks * 64) * bstride + jbase + j;
  float a0 = 0.f, a1 = 0.f, a2 = 0.f, a3 = 0.f;
  #pragma unroll 4
  for (int k = 0; k < 64; k += 4) {
    a0 += ap[(k + 0) * astride] * bp[(k + 0) * bstride];
    a1 += ap[(k + 1) * astride] * bp[(k + 1) * bstride];
    a2 += ap[(k + 2) * astride] * bp[(k + 2) * bstride];
    a3 += ap[(k + 3) * astride] * bp[(k + 3) * bstride];
  }
  red[t] = (a0 + a1) + (a2 + a3);
  __syncthreads();
  if (t < 64) {
    float v = red[t] + red[64 + t] + red[128 + t] + red[192 + t];
    ws[dstBase + t * dstStride] = v;
  }
}

// matvec helpers: out[t] = bias + sum_k x[bi][k] * W5T[u][t][k], for 8 batches
__device__ __forceinline__ void mv_single(const float* __restrict__ ws, int u,
                                          const float* xs, int t, float* r) {
  float bq = ws[OFF_B5 + u * 256 + t];
  #pragma unroll
  for (int bi = 0; bi < TB; ++bi) r[bi] = bq;
  const float* w = ws + OFF_W5T + u * 16384 + t * 64;
  #pragma unroll
  for (int k4 = 0; k4 < 16; ++k4) {
    float4 w4 = *(const float4*)(w + k4 * 4);
    #pragma unroll
    for (int bi = 0; bi < TB; ++bi) {
      float4 x4 = *(const float4*)&xs[bi * 68 + k4 * 4];
      r[bi] += x4.x * w4.x + x4.y * w4.y + x4.z * w4.z + x4.w * w4.w;
    }
  }
}
__device__ __forceinline__ void mv_pair(const float* __restrict__ ws, int u1, int u2,
                                        const float* xs, int t, float* r1, float* r2) {
  float b1 = ws[OFF_B5 + u1 * 256 + t], b2 = ws[OFF_B5 + u2 * 256 + t];
  #pragma unroll
  for (int bi = 0; bi < TB; ++bi) { r1[bi] = b1; r2[bi] = b2; }
  const float* w1 = ws + OFF_W5T + u1 * 16384 + t * 64;
  const float* w2 = ws + OFF_W5T + u2 * 16384 + t * 64;
  #pragma unroll
  for (int k4 = 0; k4 < 16; ++k4) {
    float4 a4 = *(const float4*)(w1 + k4 * 4);
    float4 c4 = *(const float4*)(w2 + k4 * 4);
    #pragma unroll
    for (int bi = 0; bi < TB; ++bi) {
      float4 x4 = *(const float4*)&xs[bi * 68 + k4 * 4];
      r1[bi] += x4.x * a4.x + x4.y * a4.y + x4.z * a4.z + x4.w * a4.w;
      r2[bi] += x4.x * c4.x + x4.y * c4.y + x4.z * c4.z + x4.w * c4.w;
    }
  }
}

// ===================== K2: attention up to feat_pre (+ sigma block) =====================
__global__ __launch_bounds__(256)
void k2_attn(const float* __restrict__ z, const float* __restrict__ rw,
             const float* __restrict__ az, const float* __restrict__ arw,
             const float* __restrict__ acz, float* __restrict__ ws) {
  __shared__ float sm[SMEM_K2];
  const int t = threadIdx.x;
  const int wv = t >> 6, ln = t & 63;

  if (blockIdx.x == 512) {
    // ---------- sigma: power-by-squaring on G (64x64), Rayleigh vs fp32 G ----------
    float* GO = sm;
    float* HA = sm + 4352;
    float* HB = sm + 8704;
    for (int e = t; e < 4096; e += 256) {
      int i = e >> 6, j = e & 63;
      GO[i * 68 + j] = ws[OFF_G + e];
    }
    __syncthreads();
    {
      float tv = (t < 64) ? GO[t * 68 + t] : 0.f;
      #pragma unroll
      for (int m = 32; m >= 1; m >>= 1) tv += __shfl_xor(tv, m, 64);
      if (t == 0) sm[13056] = (tv > 0.f) ? 1.f / tv : 0.f;
    }
    __syncthreads();
    {
      float inv0 = sm[13056];
      for (int e = t; e < 4096; e += 256) {
        int i = e >> 6, j = e & 63;
        HA[i * 68 + j] = GO[i * 68 + j] * inv0;
      }
    }
    __syncthreads();
    for (int it = 0; it < SQUARINGS; ++it) {
      float* src = (it & 1) ? HB : HA;
      float* dst = (it & 1) ? HA : HB;
      float cb[64];
      #pragma unroll
      for (int k = 0; k < 64; ++k) cb[k] = src[k * 68 + ln];
      #pragma unroll
      for (int r = 0; r < 16; ++r) {
        int i = r * 4 + wv;
        float acc = 0.f;
        #pragma unroll
        for (int k4 = 0; k4 < 16; ++k4) {
          float4 a4 = *(const float4*)&src[i * 68 + k4 * 4];
          acc += a4.x * cb[k4 * 4] + a4.y * cb[k4 * 4 + 1] + a4.z * cb[k4 * 4 + 2] + a4.w * cb[k4 * 4 + 3];
        }
        dst[i * 68 + ln] = acc;
      }
      __syncthreads();
      {
        float tv = (t < 64) ? dst[t * 68 + t] : 0.f;
        #pragma unroll
        for (int m = 32; m >= 1; m >>= 1) tv += __shfl_xor(tv, m, 64);
        if (t == 0) sm[13056] = (tv > 0.f) ? 1.f / tv : 0.f;
      }
      __syncthreads();
      {
        float sc = sm[13056];
        #pragma unroll
        for (int r = 0; r < 16; ++r) dst[(r * 4 + wv) * 68 + ln] *= sc;
      }
      __syncthreads();
    }
    float* H = (SQUARINGS & 1) ? HB : HA;
    if (t < 64) {
      float cn = 0.f;
      for (int i = 0; i < 64; ++i) { float h = H[i * 68 + t]; cn += h * h; }
      float bv = cn; int bj = t;
      #pragma unroll
      for (int m = 32; m >= 1; m >>= 1) {
        float ov = __shfl_xor(bv, m, 64);
        int   oj = __shfl_xor(bj, m, 64);
        if (ov > bv || (ov == bv && oj < bj)) { bv = ov; bj = oj; }
      }
      if (t == 0) sm[13057] = (float)bj;
    }
    __syncthreads();
    {
      int jmax = (int)sm[13057];
      if (t < 64) sm[13060 + t] = H[t * 68 + jmax];
    }
    __syncthreads();
    if (t < 64) {
      float vi = sm[13060 + t];
      float y = 0.f;
      #pragma unroll 4
      for (int k = 0; k < 64; ++k) y += GO[t * 68 + k] * sm[13060 + k];
      float num = vi * y, den = vi * vi;
      #pragma unroll
      for (int m = 32; m >= 1; m >>= 1) {
        num += __shfl_xor(num, m, 64);
        den += __shfl_xor(den, m, 64);
      }
      if (t == 0) {
        float lam = (den > 1e-37f) ? num / den : 0.f;
        lam = fmaxf(lam, 0.f);
        float sg = sqrtf(lam);
        ws[OFF_RS] = 1.f / fmaxf(sg, 1e-8f);
      }
    }
    return;
  }

  // ---------- main: 512 blocks x 8 batches ----------
  const int b0 = blockIdx.x * TB;
  for (int e = t; e < TB * 64; e += 256) {
    int bi = e >> 6, d = e & 63; int bb = b0 + bi;
    sm[S_ZS   + bi * 68 + d] = z[bb * 64 + d];
    sm[S_AZS  + bi * 68 + d] = az[bb * 64 + d];
    sm[S_ACZS + bi * 68 + d] = acz[bb * 64 + d];
  }
  { int bi = t >> 5, d = t & 31; sm[S_RWS + bi * 36 + d] = rw[(b0 + bi) * 32 + d]; }
  if (t < 128) { int bi = t >> 4, d = t & 15; sm[S_ARWS + bi * 20 + d] = arw[(b0 + bi) * 16 + d]; }
  __syncthreads();

  float qr[TB], klr[TB], kcr[TB], vlr[TB], vcr[TB];
  mv_single(ws, 0, sm + S_ZS, t, qr);
  mv_pair(ws, 1, 2, sm + S_AZS, t, klr, vlr);
  mv_pair(ws, 3, 4, sm + S_ACZS, t, kcr, vcr);

  #pragma unroll
  for (int bi = 0; bi < TB; ++bi) sm[S_QFP + bi * 260 + t] = qr[bi];

  // lat/code score reductions
  #pragma unroll
  for (int bi = 0; bi < TB; ++bi) {
    float pL = qr[bi] * klr[bi];
    float pC = qr[bi] * kcr[bi];
    #pragma unroll
    for (int m = 32; m >= 1; m >>= 1) { pL += __shfl_xor(pL, m, 64); pC += __shfl_xor(pC, m, 64); }
    if (ln == 0) { sm[S_RED + bi * 16 + wv] = pL; sm[S_RED + bi * 16 + 4 + wv] = pC; }
  }
  if (wv == 0) {
    #pragma unroll
    for (int bi = 0; bi < TB; ++bi) {
      float a = sm[S_ZS + bi * 68 + ln] - sm[S_AZS + bi * 68 + ln];
      float c = sm[S_ZS + bi * 68 + ln] - sm[S_ACZS + bi * 68 + ln];
      float dL = a * a, dC = c * c;
      #pragma unroll
      for (int m = 32; m >= 1; m >>= 1) { dL += __shfl_xor(dL, m, 64); dC += __shfl_xor(dC, m, 64); }
      if (ln == 0) { sm[S_RED + bi * 16 + 8] = dL; sm[S_RED + bi * 16 + 9] = dC; }
    }
  }
  __syncthreads();

  if (t < TB) {
    float pL = sm[S_RED + t * 16 + 0] + sm[S_RED + t * 16 + 1] + sm[S_RED + t * 16 + 2] + sm[S_RED + t * 16 + 3];
    float pC = sm[S_RED + t * 16 + 4] + sm[S_RED + t * 16 + 5] + sm[S_RED + t * 16 + 6] + sm[S_RED + t * 16 + 7];
    sm[S_SW + t * 52 + 48] = pL * 0.0625f - sm[S_RED + t * 16 + 8];
    sm[S_SW + t * 52 + 49] = pC * 0.0625f - sm[S_RED + t * 16 + 9];
  }

  // chart scores: 384 tasks (s,bi)
  for (int jb = t; jb < 48 * TB; jb += 256) {
    int s = jb >> 3, bi = jb & 7;
    const float* krow = ws + OFF_KALL + s * 256;
    float dot = 0.f;
    #pragma unroll 4
    for (int k4 = 0; k4 < 64; ++k4) {
      float4 q4 = *(const float4*)&sm[S_QFP + bi * 260 + k4 * 4];
      float4 kk = *(const float4*)(krow + k4 * 4);
      dot += q4.x * kk.x + q4.y * kk.y + q4.z * kk.z + q4.w * kk.w;
    }
    const float* anc = ws + OFF_ANC + s * 64;
    float d2 = 0.f;
    #pragma unroll 4
    for (int k4 = 0; k4 < 16; ++k4) {
      float4 z4 = *(const float4*)&sm[S_ZS + bi * 68 + k4 * 4];
      float4 a4 = *(const float4*)(anc + k4 * 4);
      float d0 = z4.x - a4.x, d1 = z4.y - a4.y, d2_ = z4.z - a4.z, d3 = z4.w - a4.w;
      d2 += d0 * d0 + d1 * d1 + d2_ * d2_ + d3 * d3;
    }
    float rwv = (s < 16) ? sm[S_ARWS + bi * 20 + s] : sm[S_RWS + bi * 36 + (s - 16)];
    sm[S_SW + bi * 52 + s] = rwv * dot * 0.0625f - d2;
  }
  __syncthreads();

  // softmax + fold routing weights
  if (t < TB) {
    float* swr = &sm[S_SW + t * 52];
    float mx = -1e30f;
    for (int s = 0; s < 50; ++s) mx = fmaxf(mx, swr[s]);
    float sum = 0.f;
    for (int s = 0; s < 50; ++s) { float ev = __expf(swr[s] - mx); swr[s] = ev; sum += ev; }
    float inv = 1.f / sum;
    for (int j = 0; j < 16; ++j) swr[j]      *= inv * sm[S_ARWS + t * 20 + j];
    for (int k = 0; k < 32; ++k) swr[16 + k] *= inv * sm[S_RWS + t * 36 + k];
    swr[48] *= inv;
    swr[49] *= inv;
  }
  __syncthreads();

  // feat_pre column t for 8 batches -> global FP
  {
    float acc[TB];
    #pragma unroll
    for (int bi = 0; bi < TB; ++bi)
      acc[bi] = sm[S_SW + bi * 52 + 48] * vlr[bi] + sm[S_SW + bi * 52 + 49] * vcr[bi];
    for (int s = 0; s < 48; ++s) {
      float v = ws[OFF_VALL + s * 256 + t];
      #pragma unroll
      for (int bi = 0; bi < TB; ++bi) acc[bi] += sm[S_SW + bi * 52 + s] * v;
    }
    #pragma unroll
    for (int bi = 0; bi < TB; ++bi) ws[OFF_FP + (b0 + bi) * 256 + t] = acc[bi];
  }
}

// ===================== K2c: g = FP @ M, projection, output =====================
#define SC_FP 0      // [16][260]
#define SC_M  4160   // [64][68]
__global__ __launch_bounds__(256)
void k2c_out(const float* __restrict__ ctrl, const float* __restrict__ ecov,
             const float* __restrict__ fb, const float* __restrict__ ws,
             float* __restrict__ out) {
  __shared__ float sm[8512];
  const int t = threadIdx.x;
  const int wv = t >> 6, d = t & 63;
  const int b0 = blockIdx.x * 16;

  for (int e = t * 4; e < 4096; e += 1024) {
    int bi = e >> 8, k = e & 255;
    float4 v = *(const float4*)(ws + OFF_FP + (b0 + bi) * 256 + k);
    *(float4*)&sm[SC_FP + bi * 260 + k] = v;
  }

  float acc0 = 0.f, acc1 = 0.f, acc2 = 0.f, acc3 = 0.f;
  for (int tc = 0; tc < 4; ++tc) {
    __syncthreads();
    for (int e = t * 4; e < 4096; e += 1024) {
      int kr = e >> 6, dd = e & 63;
      float4 v = *(const float4*)(ws + OFF_M + (tc * 64 + kr) * 64 + dd);
      *(float4*)&sm[SC_M + kr * 68 + dd] = v;
    }
    __syncthreads();
    #pragma unroll
    for (int k4 = 0; k4 < 16; ++k4) {
      int kk = tc * 64 + k4 * 4;
      float m0 = sm[SC_M + (k4 * 4 + 0) * 68 + d];
      float m1 = sm[SC_M + (k4 * 4 + 1) * 68 + d];
      float m2 = sm[SC_M + (k4 * 4 + 2) * 68 + d];
      float m3 = sm[SC_M + (k4 * 4 + 3) * 68 + d];
      float4 f0 = *(const float4*)&sm[SC_FP + (wv + 0) * 260 + kk];
      float4 f1 = *(const float4*)&sm[SC_FP + (wv + 4) * 260 + kk];
      float4 f2 = *(const float4*)&sm[SC_FP + (wv + 8) * 260 + kk];
      float4 f3 = *(const float4*)&sm[SC_FP + (wv + 12) * 260 + kk];
      acc0 += f0.x * m0 + f0.y * m1 + f0.z * m2 + f0.w * m3;
      acc1 += f1.x * m0 + f1.y * m1 + f1.z * m2 + f1.w * m3;
      acc2 += f2.x * m0 + f2.y * m1 + f2.z * m2 + f2.w * m3;
      acc3 += f3.x * m0 + f3.y * m1 + f3.z * m2 + f3.w * m3;
    }
  }

  const float rs = ws[OFF_RS];
  const float fbv = fb[d];
  #pragma unroll
  for (int s = 0; s < 4; ++s) {
    float g = (s == 0) ? acc0 : (s == 1) ? acc1 : (s == 2) ? acc2 : acc3;
    int bi = wv + s * 4;
    int bb = b0 + bi;
    float c = ctrl[bb * 64 + d];
    float e = ecov[bb * 64 + d];
    float gc = g * c, ge = g * e, ec = e * c, ee = e * e, fc = fbv * c, fe = fbv * e;
    #pragma unroll
    for (int m = 32; m >= 1; m >>= 1) {
      gc += __shfl_xor(gc, m, 64);
      ge += __shfl_xor(ge, m, 64);
      ec += __shfl_xor(ec, m, 64);
      ee += __shfl_xor(ee, m, 64);
      fc += __shfl_xor(fc, m, 64);
      fe += __shfl_xor(fe, m, 64);
    }
    if ((t & 63) == 0) {
      float A, Bv;
      if (ee > 1e-8f) { float r = ec / ee; A = gc - ge * r; Bv = fc - fe * r; }
      else { A = gc; Bv = fc; }
      out[bb] = A * rs + Bv;
    }
  }
}

extern "C" void kernel_launch(void* const* d_in, const int* in_sizes, int n_in,
                              void* d_out, int out_size, void* d_ws, size_t ws_size,
                              hipStream_t stream) {
  const float* z     = (const float*)d_in[0];
  const float* rw    = (const float*)d_in[1];
  const float* az    = (const float*)d_in[2];
  const float* arw   = (const float*)d_in[3];
  const float* acz   = (const float*)d_in[4];
  const float* ctrl  = (const float*)d_in[5];
  const float* ecov  = (const float*)d_in[6];
  const float* chemb = (const float*)d_in[7];
  const float* chanc = (const float*)d_in[8];
  const float* aemb  = (const float*)d_in[9];
  const float* aanc  = (const float*)d_in[10];
  const float* zW    = (const float*)d_in[11];
  const float* zb    = (const float*)d_in[12];
  const float* latW  = (const float*)d_in[13];
  const float* latb  = (const float*)d_in[14];
  const float* codeW = (const float*)d_in[15];
  const float* codeb = (const float*)d_in[16];
  const float* Wq    = (const float*)d_in[17];
  const float* Wk    = (const float*)d_in[18];
  const float* Wv    = (const float*)d_in[19];
  const float* Wo    = (const float*)d_in[20];
  const float* fW    = (const float*)d_in[21];
  const float* fb    = (const float*)d_in[22];
  float* ws  = (float*)d_ws;
  float* out = (float*)d_out;

  k1_fold<<<2005, 256, 0, stream>>>(chemb, aemb, zW, zb, latW, latb, codeW, codeb,
                                    Wq, Wk, Wv, Wo, fW, aanc, chanc, ws);
  k2_attn<<<513, 256, 0, stream>>>(z, rw, az, arw, acz, ws);
  k2c_out<<<256, 256, 0, stream>>>(ctrl, ecov, fb, ws, out);
}

// Round 3
// 191.328 us; speedup vs baseline: 2.2870x; 2.2870x over previous
//
#include <hip/hip_runtime.h>

// B=4096, D=64, DM=256, K=32, KA=16, S=50
#define B_N 4096
#define TB 8
#define SQUARINGS 8

// ---- workspace layout (float offsets); ~558 KB ----
#define OFF_W5T  0        // 5 x [256 j][64 k] transposed folded mats: q,klat,vlat,kcode,vcode
#define OFF_B5   81920    // 5 x [256]
#define OFF_KALL 83200    // [48][256] rows 0..15 achart@Wk, 16..47 chart@Wk
#define OFF_VALL 95488    // [48][256] @Wv
#define OFF_ANC  107776   // [48][64] anchors (achart then chart)
#define OFF_M    110848   // [256 k][64 d]  Wo @ form_W
#define OFF_G    127232   // [64][64] form_W^T form_W
#define OFF_RS   131328   // 1/sigma (+pad)
#define OFF_A    131392   // [4096] sigma-scaled part
#define OFF_Bc   135488   // [4096] sigma-free part

// ---- k2 LDS layout (floats) ----
#define S_ZS    0         // [8][68]
#define S_AZS   544
#define S_ACZS  1088
#define S_RWS   1632      // [8][36]
#define S_ARWS  1920      // [8][20]
#define S_QFP   2080      // [8][260]  q, later feat_pre
#define S_SW    4160      // [8][52]
#define S_RED   4576      // [8][16]
#define S_MST   4704      // [64][68] M chunk stage
#define SMEM_K2 13200     // sigma branch uses up to 13124

// ===================== K1: weight folds, 2005 light blocks =====================
__global__ __launch_bounds__(256)
void k1_fold(const float* __restrict__ chart_emb, const float* __restrict__ a_chart_emb,
             const float* __restrict__ zW, const float* __restrict__ zb,
             const float* __restrict__ latW, const float* __restrict__ latb,
             const float* __restrict__ codeW, const float* __restrict__ codeb,
             const float* __restrict__ Wq, const float* __restrict__ Wk,
             const float* __restrict__ Wv, const float* __restrict__ Wo,
             const float* __restrict__ fW, const float* __restrict__ ach_anchor,
             const float* __restrict__ ch_anchor, float* __restrict__ ws) {
  __shared__ float red[256];
  const int t = threadIdx.x;
  const int b = blockIdx.x;

  if (b == 2004) {   // anchor copy [48][64]
    for (int e = t; e < 3072; e += 256) {
      int s = e >> 6, d = e & 63;
      ws[OFF_ANC + e] = (s < 16) ? ach_anchor[s * 64 + d] : ch_anchor[(s - 16) * 64 + d];
    }
    return;
  }

  const float* Arow; const float* Bm;
  int astride = 1, bstride = 256, jbase = 0, dstBase, dstStride = 1;
  if (b < 1300) {                       // W5T + biases
    int u = b / 260, r = b - u * 260;
    int i = r >> 2, jc = r & 3; jbase = jc * 64;
    const float* Amat = (u == 0) ? zW : (u <= 2 ? latW : codeW);
    const float* bias = (u == 0) ? zb : (u <= 2 ? latb : codeb);
    Bm = (u == 0) ? Wq : ((u == 1 || u == 3) ? Wk : Wv);
    if (i < 64) {
      Arow = Amat + i * 256;
      dstBase = OFF_W5T + u * 16384 + jbase * 64 + i;
      dstStride = 64;
    } else {
      Arow = bias;
      dstBase = OFF_B5 + u * 256 + jbase;
    }
  } else if (b < 1684) {                // KALL/VALL
    int rr = b - 1300; int row = rr >> 2, jc = rr & 3; jbase = jc * 64;
    int s = (row < 48) ? row : row - 48;
    Bm = (row < 48) ? Wk : Wv;
    Arow = (s < 16) ? (a_chart_emb + s * 256) : (chart_emb + (s - 16) * 256);
    dstBase = OFF_KALL + row * 256 + jbase;
  } else if (b < 1940) {                // M
    int i = b - 1684;
    Arow = Wo + i * 256; Bm = fW; bstride = 64;
    dstBase = OFF_M + i * 64;
  } else {                              // G
    int i = b - 1940;
    Arow = fW + i; astride = 64; Bm = fW; bstride = 64;
    dstBase = OFF_G + i * 64;
  }

  const int j = t & 63, ks = t >> 6;
  const float* ap = Arow + (ks * 64) * astride;
  const float* bp = Bm + (ks * 64) * bstride + jbase + j;
  float a0 = 0.f, a1 = 0.f, a2 = 0.f, a3 = 0.f;
  #pragma unroll 4
  for (int k = 0; k < 64; k += 4) {
    a0 += ap[(k + 0) * astride] * bp[(k + 0) * bstride];
    a1 += ap[(k + 1) * astride] * bp[(k + 1) * bstride];
    a2 += ap[(k + 2) * astride] * bp[(k + 2) * bstride];
    a3 += ap[(k + 3) * astride] * bp[(k + 3) * bstride];
  }
  red[t] = (a0 + a1) + (a2 + a3);
  __syncthreads();
  if (t < 64) {
    float v = red[t] + red[64 + t] + red[128 + t] + red[192 + t];
    ws[dstBase + t * dstStride] = v;
  }
}

// one matvec at a time: r[bi] = bias[t] + sum_k x[bi][k] * W5T[u][t][k]
__device__ __forceinline__ void mv(const float* __restrict__ ws, int u,
                                   const float* xs, int t, float* r) {
  const float* w = ws + OFF_W5T + u * 16384 + t * 64;
  float bq = ws[OFF_B5 + u * 256 + t];
  #pragma unroll
  for (int bi = 0; bi < TB; ++bi) r[bi] = bq;
  #pragma unroll 4
  for (int k4 = 0; k4 < 16; ++k4) {
    float4 w4 = *(const float4*)(w + k4 * 4);
    #pragma unroll
    for (int bi = 0; bi < TB; ++bi) {
      float4 x4 = *(const float4*)&xs[bi * 68 + k4 * 4];
      r[bi] += x4.x * w4.x + x4.y * w4.y + x4.z * w4.z + x4.w * w4.w;
    }
  }
}

// ===================== K2: everything per-batch (+ sigma block) =====================
__global__ __launch_bounds__(256, 4)
void k2_main(const float* __restrict__ z, const float* __restrict__ rw,
             const float* __restrict__ az, const float* __restrict__ arw,
             const float* __restrict__ acz, const float* __restrict__ ctrl,
             const float* __restrict__ ecov, const float* __restrict__ fb,
             float* __restrict__ ws) {
  __shared__ __align__(16) float sm[SMEM_K2];
  const int t = threadIdx.x;
  const int wv = t >> 6, ln = t & 63;

  if (blockIdx.x == 512) {
    // ---------- sigma: 8 matrix squarings of G (trace-normalized), Rayleigh on fp32 G ----------
    float* GO = sm;
    float* HA = sm + 4352;
    float* HB = sm + 8704;
    for (int e = t; e < 4096; e += 256) {
      int i = e >> 6, j = e & 63;
      GO[i * 68 + j] = ws[OFF_G + e];
    }
    __syncthreads();
    {
      float tv = (t < 64) ? GO[t * 68 + t] : 0.f;
      #pragma unroll
      for (int m = 32; m >= 1; m >>= 1) tv += __shfl_xor(tv, m, 64);
      if (t == 0) sm[13056] = (tv > 0.f) ? 1.f / tv : 0.f;
    }
    __syncthreads();
    {
      float inv0 = sm[13056];
      for (int e = t; e < 4096; e += 256) {
        int i = e >> 6, j = e & 63;
        HA[i * 68 + j] = GO[i * 68 + j] * inv0;
      }
    }
    __syncthreads();
    for (int it = 0; it < SQUARINGS; ++it) {
      float* src = (it & 1) ? HB : HA;
      float* dst = (it & 1) ? HA : HB;
      float acc16[16];
      #pragma unroll
      for (int r = 0; r < 16; ++r) acc16[r] = 0.f;
      for (int half = 0; half < 2; ++half) {        // 32-wide column cache halves
        float cb[32];
        #pragma unroll
        for (int k = 0; k < 32; ++k) cb[k] = src[(half * 32 + k) * 68 + ln];
        #pragma unroll
        for (int r = 0; r < 16; ++r) {
          int i = r * 4 + wv;
          float a = 0.f;
          #pragma unroll
          for (int k4 = 0; k4 < 8; ++k4) {
            float4 a4 = *(const float4*)&src[i * 68 + half * 32 + k4 * 4];
            a += a4.x * cb[k4 * 4] + a4.y * cb[k4 * 4 + 1] + a4.z * cb[k4 * 4 + 2] + a4.w * cb[k4 * 4 + 3];
          }
          acc16[r] += a;
        }
      }
      #pragma unroll
      for (int r = 0; r < 16; ++r) dst[(r * 4 + wv) * 68 + ln] = acc16[r];
      __syncthreads();
      {
        float tv = (t < 64) ? dst[t * 68 + t] : 0.f;
        #pragma unroll
        for (int m = 32; m >= 1; m >>= 1) tv += __shfl_xor(tv, m, 64);
        if (t == 0) sm[13056] = (tv > 0.f) ? 1.f / tv : 0.f;
      }
      __syncthreads();
      {
        float sc = sm[13056];
        #pragma unroll
        for (int r = 0; r < 16; ++r) dst[(r * 4 + wv) * 68 + ln] *= sc;
      }
      __syncthreads();
    }
    float* H = (SQUARINGS & 1) ? HB : HA;
    if (t < 64) {
      float cn = 0.f;
      for (int i = 0; i < 64; ++i) { float h = H[i * 68 + t]; cn += h * h; }
      float bv = cn; int bj = t;
      #pragma unroll
      for (int m = 32; m >= 1; m >>= 1) {
        float ov = __shfl_xor(bv, m, 64);
        int   oj = __shfl_xor(bj, m, 64);
        if (ov > bv || (ov == bv && oj < bj)) { bv = ov; bj = oj; }
      }
      if (t == 0) sm[13057] = (float)bj;
    }
    __syncthreads();
    {
      int jmax = (int)sm[13057];
      if (t < 64) sm[13060 + t] = H[t * 68 + jmax];
    }
    __syncthreads();
    if (t < 64) {
      float vi = sm[13060 + t];
      float y = 0.f;
      #pragma unroll 4
      for (int k = 0; k < 64; ++k) y += GO[t * 68 + k] * sm[13060 + k];
      float num = vi * y, den = vi * vi;
      #pragma unroll
      for (int m = 32; m >= 1; m >>= 1) {
        num += __shfl_xor(num, m, 64);
        den += __shfl_xor(den, m, 64);
      }
      if (t == 0) {
        float lam = (den > 1e-37f) ? num / den : 0.f;
        lam = fmaxf(lam, 0.f);
        float sg = sqrtf(lam);
        ws[OFF_RS] = 1.f / fmaxf(sg, 1e-8f);
      }
    }
    return;
  }

  // ---------- main: 512 blocks x 8 batches ----------
  const int b0 = blockIdx.x * TB;
  for (int e = t; e < TB * 64; e += 256) {
    int bi = e >> 6, d = e & 63; int bb = b0 + bi;
    sm[S_ZS   + bi * 68 + d] = z[bb * 64 + d];
    sm[S_AZS  + bi * 68 + d] = az[bb * 64 + d];
    sm[S_ACZS + bi * 68 + d] = acz[bb * 64 + d];
  }
  { int bi = t >> 5, d = t & 31; sm[S_RWS + bi * 36 + d] = rw[(b0 + bi) * 32 + d]; }
  if (t < 128) { int bi = t >> 4, d = t & 15; sm[S_ARWS + bi * 20 + d] = arw[(b0 + bi) * 16 + d]; }
  __syncthreads();

  // --- q (kept live briefly), k_lat / k_code consumed immediately ---
  float qr[TB];
  mv(ws, 0, sm + S_ZS, t, qr);
  #pragma unroll
  for (int bi = 0; bi < TB; ++bi) sm[S_QFP + bi * 260 + t] = qr[bi];
  {
    float kr[TB];
    mv(ws, 1, sm + S_AZS, t, kr);
    #pragma unroll
    for (int bi = 0; bi < TB; ++bi) {
      float p = qr[bi] * kr[bi];
      #pragma unroll
      for (int m = 32; m >= 1; m >>= 1) p += __shfl_xor(p, m, 64);
      if (ln == 0) sm[S_RED + bi * 16 + wv] = p;
    }
  }
  {
    float kr[TB];
    mv(ws, 3, sm + S_ACZS, t, kr);
    #pragma unroll
    for (int bi = 0; bi < TB; ++bi) {
      float p = qr[bi] * kr[bi];
      #pragma unroll
      for (int m = 32; m >= 1; m >>= 1) p += __shfl_xor(p, m, 64);
      if (ln == 0) sm[S_RED + bi * 16 + 4 + wv] = p;
    }
  }
  if (wv == 0) {    // lat/code latent distances
    #pragma unroll
    for (int bi = 0; bi < TB; ++bi) {
      float a = sm[S_ZS + bi * 68 + ln] - sm[S_AZS + bi * 68 + ln];
      float c = sm[S_ZS + bi * 68 + ln] - sm[S_ACZS + bi * 68 + ln];
      float dL = a * a, dC = c * c;
      #pragma unroll
      for (int m = 32; m >= 1; m >>= 1) { dL += __shfl_xor(dL, m, 64); dC += __shfl_xor(dC, m, 64); }
      if (ln == 0) { sm[S_RED + bi * 16 + 8] = dL; sm[S_RED + bi * 16 + 9] = dC; }
    }
  }
  // --- v_lat / v_code, kept in regs until feat_pre ---
  float vlr[TB], vcr[TB];
  mv(ws, 2, sm + S_AZS, t, vlr);
  mv(ws, 4, sm + S_ACZS, t, vcr);
  __syncthreads();

  if (t < TB) {
    float pL = sm[S_RED + t * 16 + 0] + sm[S_RED + t * 16 + 1] + sm[S_RED + t * 16 + 2] + sm[S_RED + t * 16 + 3];
    float pC = sm[S_RED + t * 16 + 4] + sm[S_RED + t * 16 + 5] + sm[S_RED + t * 16 + 6] + sm[S_RED + t * 16 + 7];
    sm[S_SW + t * 52 + 48] = pL * 0.0625f - sm[S_RED + t * 16 + 8];
    sm[S_SW + t * 52 + 49] = pC * 0.0625f - sm[S_RED + t * 16 + 9];
  }

  // chart scores: 384 tasks (s,bi)
  for (int jb = t; jb < 48 * TB; jb += 256) {
    int s = jb >> 3, bi = jb & 7;
    const float* krow = ws + OFF_KALL + s * 256;
    float dot = 0.f;
    #pragma unroll 4
    for (int k4 = 0; k4 < 64; ++k4) {
      float4 q4 = *(const float4*)&sm[S_QFP + bi * 260 + k4 * 4];
      float4 kk = *(const float4*)(krow + k4 * 4);
      dot += q4.x * kk.x + q4.y * kk.y + q4.z * kk.z + q4.w * kk.w;
    }
    const float* anc = ws + OFF_ANC + s * 64;
    float d2 = 0.f;
    #pragma unroll 4
    for (int k4 = 0; k4 < 16; ++k4) {
      float4 z4 = *(const float4*)&sm[S_ZS + bi * 68 + k4 * 4];
      float4 a4 = *(const float4*)(anc + k4 * 4);
      float d0 = z4.x - a4.x, d1 = z4.y - a4.y, dd = z4.z - a4.z, d3 = z4.w - a4.w;
      d2 += d0 * d0 + d1 * d1 + dd * dd + d3 * d3;
    }
    float rwv = (s < 16) ? sm[S_ARWS + bi * 20 + s] : sm[S_RWS + bi * 36 + (s - 16)];
    sm[S_SW + bi * 52 + s] = rwv * dot * 0.0625f - d2;
  }
  __syncthreads();

  // softmax + fold routing weights
  if (t < TB) {
    float* swr = &sm[S_SW + t * 52];
    float mx = -1e30f;
    for (int s = 0; s < 50; ++s) mx = fmaxf(mx, swr[s]);
    float sum = 0.f;
    for (int s = 0; s < 50; ++s) { float ev = __expf(swr[s] - mx); swr[s] = ev; sum += ev; }
    float inv = 1.f / sum;
    for (int j = 0; j < 16; ++j) swr[j]      *= inv * sm[S_ARWS + t * 20 + j];
    for (int k = 0; k < 32; ++k) swr[16 + k] *= inv * sm[S_RWS + t * 36 + k];
    swr[48] *= inv;
    swr[49] *= inv;
  }
  __syncthreads();

  // feat_pre column t for 8 batches -> S_QFP (overwrites q)
  {
    float acc[TB];
    #pragma unroll
    for (int bi = 0; bi < TB; ++bi)
      acc[bi] = sm[S_SW + bi * 52 + 48] * vlr[bi] + sm[S_SW + bi * 52 + 49] * vcr[bi];
    for (int sc = 0; sc < 12; ++sc) {
      float v0 = ws[OFF_VALL + (sc * 4 + 0) * 256 + t];
      float v1 = ws[OFF_VALL + (sc * 4 + 1) * 256 + t];
      float v2 = ws[OFF_VALL + (sc * 4 + 2) * 256 + t];
      float v3 = ws[OFF_VALL + (sc * 4 + 3) * 256 + t];
      #pragma unroll
      for (int bi = 0; bi < TB; ++bi) {
        float4 w4 = *(const float4*)&sm[S_SW + bi * 52 + sc * 4];
        acc[bi] += w4.x * v0 + w4.y * v1 + w4.z * v2 + w4.w * v3;
      }
    }
    __syncthreads();
    #pragma unroll
    for (int bi = 0; bi < TB; ++bi) sm[S_QFP + bi * 260 + t] = acc[bi];
  }
  __syncthreads();

  // g = feat_pre @ M (M staged in 64-row LDS chunks); 2 outputs/thread
  float g0 = 0.f, g1 = 0.f;
  const int d = ln;
  for (int tc = 0; tc < 4; ++tc) {
    __syncthreads();
    for (int e = t * 4; e < 4096; e += 1024) {
      int kr = e >> 6, dd = e & 63;
      *(float4*)&sm[S_MST + kr * 68 + dd] = *(const float4*)(ws + OFF_M + (tc * 64 + kr) * 64 + dd);
    }
    __syncthreads();
    #pragma unroll 4
    for (int k4 = 0; k4 < 16; ++k4) {
      float m0 = sm[S_MST + (k4 * 4 + 0) * 68 + d];
      float m1 = sm[S_MST + (k4 * 4 + 1) * 68 + d];
      float m2 = sm[S_MST + (k4 * 4 + 2) * 68 + d];
      float m3 = sm[S_MST + (k4 * 4 + 3) * 68 + d];
      float4 f0 = *(const float4*)&sm[S_QFP + wv * 260 + tc * 64 + k4 * 4];
      float4 f1 = *(const float4*)&sm[S_QFP + (wv + 4) * 260 + tc * 64 + k4 * 4];
      g0 += f0.x * m0 + f0.y * m1 + f0.z * m2 + f0.w * m3;
      g1 += f1.x * m0 + f1.y * m1 + f1.z * m2 + f1.w * m3;
    }
  }

  // epilogue: per-batch projections -> A (needs 1/sigma), B (sigma-free)
  {
    float fbv = fb[d];
    #pragma unroll
    for (int s = 0; s < 2; ++s) {
      float g = (s == 0) ? g0 : g1;
      int bi = wv + s * 4;
      int bb = b0 + bi;
      float c = ctrl[bb * 64 + d];
      float e = ecov[bb * 64 + d];
      float gc = g * c, ge = g * e, ec = e * c, ee = e * e, fc = fbv * c, fe = fbv * e;
      #pragma unroll
      for (int m = 32; m >= 1; m >>= 1) {
        gc += __shfl_xor(gc, m, 64);
        ge += __shfl_xor(ge, m, 64);
        ec += __shfl_xor(ec, m, 64);
        ee += __shfl_xor(ee, m, 64);
        fc += __shfl_xor(fc, m, 64);
        fe += __shfl_xor(fe, m, 64);
      }
      if (ln == 0) {
        float A, Bv;
        if (ee > 1e-8f) { float r = ec / ee; A = gc - ge * r; Bv = fc - fe * r; }
        else { A = gc; Bv = fc; }
        ws[OFF_A  + bb] = A;
        ws[OFF_Bc + bb] = Bv;
      }
    }
  }
}

// ===================== K3: apply 1/sigma =====================
__global__ __launch_bounds__(256)
void k3_out(const float* __restrict__ ws, float* __restrict__ out) {
  int b = blockIdx.x * 256 + threadIdx.x;
  float rs = ws[OFF_RS];
  out[b] = ws[OFF_A + b] * rs + ws[OFF_Bc + b];
}

extern "C" void kernel_launch(void* const* d_in, const int* in_sizes, int n_in,
                              void* d_out, int out_size, void* d_ws, size_t ws_size,
                              hipStream_t stream) {
  const float* z     = (const float*)d_in[0];
  const float* rw    = (const float*)d_in[1];
  const float* az    = (const float*)d_in[2];
  const float* arw   = (const float*)d_in[3];
  const float* acz   = (const float*)d_in[4];
  const float* ctrl  = (const float*)d_in[5];
  const float* ecov  = (const float*)d_in[6];
  const float* chemb = (const float*)d_in[7];
  const float* chanc = (const float*)d_in[8];
  const float* aemb  = (const float*)d_in[9];
  const float* aanc  = (const float*)d_in[10];
  const float* zW    = (const float*)d_in[11];
  const float* zb    = (const float*)d_in[12];
  const float* latW  = (const float*)d_in[13];
  const float* latb  = (const float*)d_in[14];
  const float* codeW = (const float*)d_in[15];
  const float* codeb = (const float*)d_in[16];
  const float* Wq    = (const float*)d_in[17];
  const float* Wk    = (const float*)d_in[18];
  const float* Wv    = (const float*)d_in[19];
  const float* Wo    = (const float*)d_in[20];
  const float* fW    = (const float*)d_in[21];
  const float* fb    = (const float*)d_in[22];
  float* ws  = (float*)d_ws;
  float* out = (float*)d_out;

  k1_fold<<<2005, 256, 0, stream>>>(chemb, aemb, zW, zb, latW, latb, codeW, codeb,
                                    Wq, Wk, Wv, Wo, fW, aanc, chanc, ws);
  k2_main<<<513, 256, 0, stream>>>(z, rw, az, arw, acz, ctrl, ecov, fb, ws);
  k3_out<<<16, 256, 0, stream>>>(ws, out);
}